// Round 3
// baseline (23987.608 us; speedup 1.0000x reference)
//
#include <hip/hip_runtime.h>

#define B_ 4
#define S_ 4096
#define D_ 512
#define H_ 8
#define L_ 6
#define M_ 2048
#define DH_ 64
#define NC_ 64   // number of chunks = S/C
#define C_ 64    // chunk length

// ---------------------------------------------------------------------------
// Embedding + sinusoidal positional encoding
// x[b,s,d] = emb[tokens[b,s]][d] + PE(s,d)
// PE mirrors the numpy (NEP-50/f64) recipe exactly: freq f64, arg f64,
// sin/cos f64, single final cast to f32.
// ---------------------------------------------------------------------------
__global__ __launch_bounds__(128) void embed_kernel(const int* __restrict__ tokens,
                                                    const float* __restrict__ emb,
                                                    float* __restrict__ x) {
  int row = blockIdx.x;            // b*S + s
  int s = row & (S_ - 1);
  int tok = tokens[row];
  const float4* e = (const float4*)(emb + (size_t)tok * D_);
  float4* xo = (float4*)(x + (size_t)row * D_);
  int t = threadIdx.x;             // 128 threads, 4 floats each
  float4 ev = e[t];
  int d0 = t * 4;
  const double c64 = -9.210340371976184 / 255.0;   // -ln(10000)/(half-1)
  float pe[4];
#pragma unroll
  for (int j = 0; j < 4; j++) {
    int d = d0 + j;
    int i = (d < 256) ? d : d - 256;
    double freq = exp((double)i * c64);            // f64 freq
    double arg = (double)s * freq;                 // f64 argument
    pe[j] = (d < 256) ? (float)sin(arg) : (float)cos(arg);
  }
  float4 o;
  o.x = ev.x + pe[0];
  o.y = ev.y + pe[1];
  o.z = ev.z + pe[2];
  o.w = ev.w + pe[3];
  xo[t] = o;
}

// ---------------------------------------------------------------------------
// LayerNorm: one 64-thread wave per row of D=512
// ---------------------------------------------------------------------------
__global__ __launch_bounds__(64) void ln_kernel(const float* __restrict__ in,
                                                float* __restrict__ out,
                                                const float* __restrict__ sc,
                                                const float* __restrict__ bi) {
  int row = blockIdx.x;
  const float4* ir = (const float4*)(in + (size_t)row * D_);
  int t = threadIdx.x;
  float4 a = ir[t];
  float4 b4 = ir[t + 64];
  float sum = a.x + a.y + a.z + a.w + b4.x + b4.y + b4.z + b4.w;
  float sq  = a.x*a.x + a.y*a.y + a.z*a.z + a.w*a.w
            + b4.x*b4.x + b4.y*b4.y + b4.z*b4.z + b4.w*b4.w;
#pragma unroll
  for (int m = 1; m < 64; m <<= 1) {
    sum += __shfl_xor(sum, m);
    sq  += __shfl_xor(sq, m);
  }
  float mean = sum * (1.0f / 512.0f);
  float var  = sq * (1.0f / 512.0f) - mean * mean;
  float rstd = 1.0f / sqrtf(var + 1e-6f);
  float4 s1 = ((const float4*)sc)[t], s2 = ((const float4*)sc)[t + 64];
  float4 g1 = ((const float4*)bi)[t], g2 = ((const float4*)bi)[t + 64];
  float4 o1, o2;
  o1.x = (a.x - mean) * rstd * s1.x + g1.x;
  o1.y = (a.y - mean) * rstd * s1.y + g1.y;
  o1.z = (a.z - mean) * rstd * s1.z + g1.z;
  o1.w = (a.w - mean) * rstd * s1.w + g1.w;
  o2.x = (b4.x - mean) * rstd * s2.x + g2.x;
  o2.y = (b4.y - mean) * rstd * s2.y + g2.y;
  o2.z = (b4.z - mean) * rstd * s2.z + g2.z;
  o2.w = (b4.w - mean) * rstd * s2.w + g2.w;
  float4* orow = (float4*)(out + (size_t)row * D_);
  orow[t] = o1;
  orow[t + 64] = o2;
}

// ---------------------------------------------------------------------------
// f32 tiled GEMM: C[M,N] = op(A[M,K] @ W[K,N] + bias) (+ C residual)
// 64x64 tile, 256 threads, 4x4 micro-tile
// ---------------------------------------------------------------------------
__device__ __forceinline__ float gelu_f(float v) {
  float v3 = v * v * v;
  return 0.5f * v * (1.0f + tanhf(0.7978845608028654f * (v + 0.044715f * v3)));
}

template <int HAS_BIAS, int RESID, int DO_GELU>
__global__ __launch_bounds__(256) void gemm_kernel(const float* __restrict__ A,
                                                   const float* __restrict__ W,
                                                   const float* __restrict__ bias,
                                                   float* __restrict__ C,
                                                   int M, int N, int K) {
  __shared__ float As[16][65];   // [k][m], padded
  __shared__ float Bs[16][64];   // [k][n]
  int tid = threadIdx.x;
  int bn = blockIdx.x, bm = blockIdx.y;
  int row0 = bm * 64, col0 = bn * 64;
  int tr = tid >> 4, tc = tid & 15;       // 16x16 threads
  float acc[4][4] = {};

  int la_r = tid >> 2;               // 0..63  A row within tile
  int la_c = (tid & 3) * 4;          // 0,4,8,12
  int lb_r = tid >> 4;               // 0..15  B row within tile
  int lb_c = (tid & 15) * 4;

  for (int k0 = 0; k0 < K; k0 += 16) {
    float4 av = *(const float4*)(A + (size_t)(row0 + la_r) * K + k0 + la_c);
    As[la_c + 0][la_r] = av.x;
    As[la_c + 1][la_r] = av.y;
    As[la_c + 2][la_r] = av.z;
    As[la_c + 3][la_r] = av.w;
    float4 bv = *(const float4*)(W + (size_t)(k0 + lb_r) * N + col0 + lb_c);
    *(float4*)&Bs[lb_r][lb_c] = bv;
    __syncthreads();
#pragma unroll
    for (int kk = 0; kk < 16; kk++) {
      float a0 = As[kk][tr * 4 + 0];
      float a1 = As[kk][tr * 4 + 1];
      float a2 = As[kk][tr * 4 + 2];
      float a3 = As[kk][tr * 4 + 3];
      float4 b = *(const float4*)&Bs[kk][tc * 4];
      acc[0][0] += a0 * b.x; acc[0][1] += a0 * b.y; acc[0][2] += a0 * b.z; acc[0][3] += a0 * b.w;
      acc[1][0] += a1 * b.x; acc[1][1] += a1 * b.y; acc[1][2] += a1 * b.z; acc[1][3] += a1 * b.w;
      acc[2][0] += a2 * b.x; acc[2][1] += a2 * b.y; acc[2][2] += a2 * b.z; acc[2][3] += a2 * b.w;
      acc[3][0] += a3 * b.x; acc[3][1] += a3 * b.y; acc[3][2] += a3 * b.z; acc[3][3] += a3 * b.w;
    }
    __syncthreads();
  }

  float4 bv4 = {0.f, 0.f, 0.f, 0.f};
  if (HAS_BIAS) bv4 = *(const float4*)(bias + col0 + tc * 4);
#pragma unroll
  for (int i = 0; i < 4; i++) {
    int row = row0 + tr * 4 + i;
    float* cp = C + (size_t)row * N + col0 + tc * 4;
    float4 vv;
    vv.x = acc[i][0]; vv.y = acc[i][1]; vv.z = acc[i][2]; vv.w = acc[i][3];
    if (HAS_BIAS) { vv.x += bv4.x; vv.y += bv4.y; vv.z += bv4.z; vv.w += bv4.w; }
    if (DO_GELU) { vv.x = gelu_f(vv.x); vv.y = gelu_f(vv.y); vv.z = gelu_f(vv.z); vv.w = gelu_f(vv.w); }
    if (RESID) {
      float4 old = *(const float4*)cp;
      vv.x += old.x; vv.y += old.y; vv.z += old.z; vv.w += old.w;
    }
    *(float4*)cp = vv;
  }
}

// ---------------------------------------------------------------------------
// rotW[h][d][j] = sum_f Wq[d][h*64+f] * rot[h][f][j]   (f64 fused hash weight)
// ---------------------------------------------------------------------------
__global__ __launch_bounds__(256) void rotw_kernel(const float* __restrict__ Wq,
                                                   const float* __restrict__ rot,
                                                   double* __restrict__ rotW) {
  int idx = blockIdx.x * 256 + threadIdx.x;   // h*512*32 + d*32 + j
  int j = idx & 31;
  int d = (idx >> 5) & 511;
  int h = idx >> 14;
  double a = 0.0;
#pragma unroll 8
  for (int f = 0; f < 64; f++) {
    a += (double)Wq[(size_t)d * D_ + h * 64 + f] * (double)rot[((size_t)h * 64 + f) * 32 + j];
  }
  rotW[idx] = a;
}

// ---------------------------------------------------------------------------
// f64 LSH hash: r[j] = sum_d h[d] * rotW[h][d][j]; bucket = argmax([r,-r]).
// Block: 32 rows x 8 heads (256 threads). h rows staged in LDS.
// ---------------------------------------------------------------------------
__global__ __launch_bounds__(256) void hash_kernel(const float* __restrict__ hbuf,
                                                   const double* __restrict__ rotW,
                                                   int* __restrict__ buckets) {
  __shared__ float hs[32][512];
  int blk = blockIdx.x;
  int b = blk >> 7;                  // S/32 = 128 blocks per batch
  int s0 = (blk & 127) * 32;
  int tid = threadIdx.x;
  for (int i = tid; i < 32 * 128; i += 256) {
    int r = i >> 7, c = i & 127;
    ((float4*)hs[r])[c] = ((const float4*)(hbuf + ((size_t)(b * S_ + s0 + r)) * D_))[c];
  }
  __syncthreads();
  int r = tid >> 3, h = tid & 7;
  double acc[32];
#pragma unroll
  for (int j = 0; j < 32; j++) acc[j] = 0.0;
  const double* rw = rotW + (size_t)h * D_ * 32;
  for (int d = 0; d < 512; d++) {
    double hv = (double)hs[r][d];
    const double* rp = rw + (size_t)d * 32;
#pragma unroll
    for (int j = 0; j < 32; j++) acc[j] += hv * rp[j];
  }
  double best = acc[0];
  int bi = 0;
#pragma unroll
  for (int j = 1; j < 64; j++) {
    double val = (j < 32) ? acc[j] : -acc[j - 32];
    if (val > best) { best = val; bi = j; }
  }
  buckets[((size_t)b * H_ + h) * S_ + s0 + r] = bi;
}

// ---------------------------------------------------------------------------
// Stable counting sort by bucket (== argsort(bucket*S + pos)).
// One 64-thread block per (b,h). Each thread owns 64 consecutive positions.
// ---------------------------------------------------------------------------
__global__ __launch_bounds__(64) void sort_kernel(const int* __restrict__ buckets,
                                                  int* __restrict__ st) {
  __shared__ int hist[64][64];   // [thread][bucket]
  __shared__ int boff[64];
  int bh = blockIdx.x;
  const int* bk = buckets + (size_t)bh * S_;
  int* stb = st + (size_t)bh * S_;
  int t = threadIdx.x;
  for (int j = 0; j < 64; j++) hist[t][j] = 0;
  __syncthreads();
  for (int i = 0; i < 64; i++) {
    int s = t * 64 + i;
    hist[t][bk[s]]++;
  }
  __syncthreads();
  // per-bucket exclusive scan across threads (thread j handles bucket j)
  int run = 0;
  for (int tt = 0; tt < 64; tt++) {
    int c = hist[tt][t];
    hist[tt][t] = run;
    run += c;
  }
  boff[t] = run;
  __syncthreads();
  if (t == 0) {
    int acc = 0;
    for (int j = 0; j < 64; j++) { int c = boff[j]; boff[j] = acc; acc += c; }
  }
  __syncthreads();
  for (int i = 0; i < 64; i++) {
    int s = t * 64 + i;
    int bkt = bk[s];
    int pos = boff[bkt] + hist[t][bkt];
    hist[t][bkt] = hist[t][bkt] + 1;
    stb[pos] = s;
  }
}

// ---------------------------------------------------------------------------
// Chunked shared-QK attention. One block per (b,h,chunk).
// Keys/values: chunk n plus chunk n-1 (wrap). 64 queries x 128 keys.
// Thread layout: row r = tid>>2 (0..63), sub = tid&3 owns 32 keys.
// ---------------------------------------------------------------------------
__global__ __launch_bounds__(256) void attn_kernel(const float* __restrict__ q,
                                                   const float* __restrict__ v,
                                                   const int* __restrict__ st,
                                                   float* __restrict__ o) {
  __shared__ float Ksh[128][64];
  __shared__ float Vsh[128][64];
  int blk = blockIdx.x;
  int n = blk & (NC_ - 1);
  int bh = blk >> 6;
  int h = bh & (H_ - 1);
  int b = bh >> 3;
  const int* stbh = st + (size_t)bh * S_;
  int tid = threadIdx.x;
  int pn = (n + NC_ - 1) & (NC_ - 1);
  for (int i = tid; i < 128 * 16; i += 256) {
    int r = i >> 4, c4 = i & 15;
    int si = (r < 64) ? (n * 64 + r) : (pn * 64 + (r - 64));
    int p = stbh[si];
    size_t base = ((size_t)b * S_ + p) * D_ + h * 64;
    ((float4*)Ksh[r])[c4] = *(const float4*)(q + base + c4 * 4);
    ((float4*)Vsh[r])[c4] = *(const float4*)(v + base + c4 * 4);
  }
  __syncthreads();
  int r = tid >> 2, sub = tid & 3;
  float qr[64];
#pragma unroll
  for (int f4 = 0; f4 < 16; f4++) {
    float4 t4 = ((const float4*)Ksh[r])[f4];
    qr[f4 * 4 + 0] = t4.x; qr[f4 * 4 + 1] = t4.y;
    qr[f4 * 4 + 2] = t4.z; qr[f4 * 4 + 3] = t4.w;
  }
  float lg[32];
  float mx = -1e30f;
#pragma unroll
  for (int kk = 0; kk < 32; kk++) {
    int k = sub * 32 + kk;
    float sdot = 0.f;
#pragma unroll
    for (int f4 = 0; f4 < 16; f4++) {
      float4 kv = ((const float4*)Ksh[k])[f4];
      sdot += qr[f4 * 4 + 0] * kv.x + qr[f4 * 4 + 1] * kv.y
            + qr[f4 * 4 + 2] * kv.z + qr[f4 * 4 + 3] * kv.w;
    }
    sdot *= 0.125f;
    lg[kk] = sdot;
    mx = fmaxf(mx, sdot);
  }
  mx = fmaxf(mx, __shfl_xor(mx, 1));
  mx = fmaxf(mx, __shfl_xor(mx, 2));
  float ssum = 0.f;
#pragma unroll
  for (int kk = 0; kk < 32; kk++) {
    float p = expf(lg[kk] - mx);
    lg[kk] = p;
    ssum += p;
  }
  ssum += __shfl_xor(ssum, 1);
  ssum += __shfl_xor(ssum, 2);
  float acc[64];
#pragma unroll
  for (int f = 0; f < 64; f++) acc[f] = 0.f;
#pragma unroll
  for (int kk = 0; kk < 32; kk++) {
    int k = sub * 32 + kk;
    float w = lg[kk];
#pragma unroll
    for (int f4 = 0; f4 < 16; f4++) {
      float4 vv = ((const float4*)Vsh[k])[f4];
      acc[f4 * 4 + 0] += w * vv.x;
      acc[f4 * 4 + 1] += w * vv.y;
      acc[f4 * 4 + 2] += w * vv.z;
      acc[f4 * 4 + 3] += w * vv.w;
    }
  }
  // reduce-scatter across the 4 sub-lanes (static register indices only)
  float red[32];
#pragma unroll
  for (int j = 0; j < 32; j++) {
    float lo = acc[j], hi = acc[32 + j];
    float keep = (sub & 1) ? hi : lo;
    float send = (sub & 1) ? lo : hi;
    red[j] = keep + __shfl_xor(send, 1);
  }
  float red2[16];
#pragma unroll
  for (int j = 0; j < 16; j++) {
    float lo = red[j], hi = red[16 + j];
    float keep = (sub & 2) ? hi : lo;
    float send = (sub & 2) ? lo : hi;
    red2[j] = keep + __shfl_xor(send, 2);
  }
  int seg = (sub & 1) * 32 + (sub & 2) * 8;   // 0->0, 1->32, 2->16, 3->48
  float inv = 1.0f / ssum;
  int p = stbh[n * 64 + r];
  float* orow = o + ((size_t)b * S_ + p) * D_ + h * 64 + seg;
#pragma unroll
  for (int f4 = 0; f4 < 4; f4++) {
    float4 w4;
    w4.x = red2[f4 * 4 + 0] * inv;
    w4.y = red2[f4 * 4 + 1] * inv;
    w4.z = red2[f4 * 4 + 2] * inv;
    w4.w = red2[f4 * 4 + 3] * inv;
    *(float4*)(orow + f4 * 4) = w4;
  }
}

// ---------------------------------------------------------------------------
extern "C" void kernel_launch(void* const* d_in, const int* in_sizes, int n_in,
                              void* d_out, int out_size, void* d_ws, size_t ws_size,
                              hipStream_t stream) {
  const int*   tokens = (const int*)d_in[0];
  const float* emb    = (const float*)d_in[1];
  const float* rot    = (const float*)d_in[2];
  const float* ln1_s  = (const float*)d_in[3];
  const float* ln1_b  = (const float*)d_in[4];
  const float* Wq     = (const float*)d_in[5];
  const float* Wv     = (const float*)d_in[6];
  const float* Wo     = (const float*)d_in[7];
  const float* ln2_s  = (const float*)d_in[8];
  const float* ln2_b  = (const float*)d_in[9];
  const float* W1     = (const float*)d_in[10];
  const float* b1     = (const float*)d_in[11];
  const float* W2     = (const float*)d_in[12];
  const float* b2     = (const float*)d_in[13];
  const float* lnf_s  = (const float*)d_in[14];
  const float* lnf_b  = (const float*)d_in[15];

  float* x = (float*)d_out;                  // residual stream lives in d_out
  float* ws = (float*)d_ws;
  const size_t RS = (size_t)B_ * S_ * D_;    // 8388608
  float* hbuf = ws;
  float* qbuf = hbuf + RS;
  float* vbuf = qbuf + RS;
  float* obuf = vbuf + RS;
  float* mid  = obuf + RS;                   // 4096*2048 chunk
  int* buckets = (int*)(mid + (size_t)4096 * M_);
  int* stbuf   = buckets + B_ * H_ * S_;
  double* rotW = (double*)(stbuf + B_ * H_ * S_);   // [H][D][32], 1 MB, 8B-aligned

  const int rows = B_ * S_;                  // 16384

  embed_kernel<<<rows, 128, 0, stream>>>(tokens, emb, x);

  for (int l = 0; l < L_; l++) {
    ln_kernel<<<rows, 64, 0, stream>>>(x, hbuf, ln1_s + (size_t)l * D_, ln1_b + (size_t)l * D_);

    dim3 g1(D_ / 64, rows / 64);
    gemm_kernel<0, 0, 0><<<g1, 256, 0, stream>>>(hbuf, Wq + (size_t)l * D_ * D_, nullptr, qbuf, rows, D_, D_);
    gemm_kernel<0, 0, 0><<<g1, 256, 0, stream>>>(hbuf, Wv + (size_t)l * D_ * D_, nullptr, vbuf, rows, D_, D_);

    rotw_kernel<<<(H_ * D_ * 32) / 256, 256, 0, stream>>>(Wq + (size_t)l * D_ * D_,
                                                          rot + (size_t)l * H_ * DH_ * 32, rotW);
    hash_kernel<<<B_ * (S_ / 32), 256, 0, stream>>>(hbuf, rotW, buckets);
    sort_kernel<<<B_ * H_, 64, 0, stream>>>(buckets, stbuf);
    attn_kernel<<<B_ * H_ * NC_, 256, 0, stream>>>(qbuf, vbuf, stbuf, obuf);

    gemm_kernel<0, 1, 0><<<g1, 256, 0, stream>>>(obuf, Wo + (size_t)l * D_ * D_, nullptr, x, rows, D_, D_);

    ln_kernel<<<rows, 64, 0, stream>>>(x, hbuf, ln2_s + (size_t)l * D_, ln2_b + (size_t)l * D_);

    for (int c = 0; c < 4; c++) {
      dim3 gf1(M_ / 64, 4096 / 64);
      gemm_kernel<1, 0, 1><<<gf1, 256, 0, stream>>>(hbuf + (size_t)c * 4096 * D_,
                                                    W1 + (size_t)l * D_ * M_, b1 + (size_t)l * M_,
                                                    mid, 4096, M_, D_);
      dim3 gf2(D_ / 64, 4096 / 64);
      gemm_kernel<1, 1, 0><<<gf2, 256, 0, stream>>>(mid,
                                                    W2 + (size_t)l * M_ * D_, b2 + (size_t)l * D_,
                                                    x + (size_t)c * 4096 * D_, 4096, D_, M_);
    }
  }

  ln_kernel<<<rows, 64, 0, stream>>>(x, x, lnf_s, lnf_b);
}

// Round 4
// 12487.421 us; speedup vs baseline: 1.9209x; 1.9209x over previous
//
#include <hip/hip_runtime.h>

#define B_ 4
#define S_ 4096
#define D_ 512
#define H_ 8
#define L_ 6
#define M_ 2048
#define DH_ 64
#define NC_ 64   // number of chunks = S/C
#define C_ 64    // chunk length

// ---------------------------------------------------------------------------
// Embedding + sinusoidal positional encoding
// PE mirrors the numpy (NEP-50/f64) recipe: freq f64, arg f64, sin/cos f64,
// single final cast to f32.  (This was the round-3 correctness fix.)
// ---------------------------------------------------------------------------
__global__ __launch_bounds__(128) void embed_kernel(const int* __restrict__ tokens,
                                                    const float* __restrict__ emb,
                                                    float* __restrict__ x) {
  int row = blockIdx.x;            // b*S + s
  int s = row & (S_ - 1);
  int tok = tokens[row];
  const float4* e = (const float4*)(emb + (size_t)tok * D_);
  float4* xo = (float4*)(x + (size_t)row * D_);
  int t = threadIdx.x;             // 128 threads, 4 floats each
  float4 ev = e[t];
  int d0 = t * 4;
  const double c64 = -9.210340371976184 / 255.0;   // -ln(10000)/(half-1)
  float pe[4];
#pragma unroll
  for (int j = 0; j < 4; j++) {
    int d = d0 + j;
    int i = (d < 256) ? d : d - 256;
    double freq = exp((double)i * c64);
    double arg = (double)s * freq;
    pe[j] = (d < 256) ? (float)sin(arg) : (float)cos(arg);
  }
  float4 o;
  o.x = ev.x + pe[0];
  o.y = ev.y + pe[1];
  o.z = ev.z + pe[2];
  o.w = ev.w + pe[3];
  xo[t] = o;
}

// ---------------------------------------------------------------------------
// LayerNorm: one 64-thread wave per row of D=512
// ---------------------------------------------------------------------------
__global__ __launch_bounds__(64) void ln_kernel(const float* __restrict__ in,
                                                float* __restrict__ out,
                                                const float* __restrict__ sc,
                                                const float* __restrict__ bi) {
  int row = blockIdx.x;
  const float4* ir = (const float4*)(in + (size_t)row * D_);
  int t = threadIdx.x;
  float4 a = ir[t];
  float4 b4 = ir[t + 64];
  float sum = a.x + a.y + a.z + a.w + b4.x + b4.y + b4.z + b4.w;
  float sq  = a.x*a.x + a.y*a.y + a.z*a.z + a.w*a.w
            + b4.x*b4.x + b4.y*b4.y + b4.z*b4.z + b4.w*b4.w;
#pragma unroll
  for (int m = 1; m < 64; m <<= 1) {
    sum += __shfl_xor(sum, m);
    sq  += __shfl_xor(sq, m);
  }
  float mean = sum * (1.0f / 512.0f);
  float var  = sq * (1.0f / 512.0f) - mean * mean;
  float rstd = 1.0f / sqrtf(var + 1e-6f);
  float4 s1 = ((const float4*)sc)[t], s2 = ((const float4*)sc)[t + 64];
  float4 g1 = ((const float4*)bi)[t], g2 = ((const float4*)bi)[t + 64];
  float4 o1, o2;
  o1.x = (a.x - mean) * rstd * s1.x + g1.x;
  o1.y = (a.y - mean) * rstd * s1.y + g1.y;
  o1.z = (a.z - mean) * rstd * s1.z + g1.z;
  o1.w = (a.w - mean) * rstd * s1.w + g1.w;
  o2.x = (b4.x - mean) * rstd * s2.x + g2.x;
  o2.y = (b4.y - mean) * rstd * s2.y + g2.y;
  o2.z = (b4.z - mean) * rstd * s2.z + g2.z;
  o2.w = (b4.w - mean) * rstd * s2.w + g2.w;
  float4* orow = (float4*)(out + (size_t)row * D_);
  orow[t] = o1;
  orow[t + 64] = o2;
}

// ---------------------------------------------------------------------------
// f32 tiled GEMM: C[M,N] = op(A[M,K] @ W[K,N] + bias) (+ C residual)
// 64x64 tile, 256 threads, 4x4 micro-tile
// ---------------------------------------------------------------------------
__device__ __forceinline__ float gelu_f(float v) {
  float v3 = v * v * v;
  return 0.5f * v * (1.0f + tanhf(0.7978845608028654f * (v + 0.044715f * v3)));
}

template <int HAS_BIAS, int RESID, int DO_GELU>
__global__ __launch_bounds__(256) void gemm_kernel(const float* __restrict__ A,
                                                   const float* __restrict__ W,
                                                   const float* __restrict__ bias,
                                                   float* __restrict__ C,
                                                   int M, int N, int K) {
  __shared__ float As[16][65];   // [k][m], padded
  __shared__ float Bs[16][64];   // [k][n]
  int tid = threadIdx.x;
  int bn = blockIdx.x, bm = blockIdx.y;
  int row0 = bm * 64, col0 = bn * 64;
  int tr = tid >> 4, tc = tid & 15;       // 16x16 threads
  float acc[4][4] = {};

  int la_r = tid >> 2;               // 0..63  A row within tile
  int la_c = (tid & 3) * 4;          // 0,4,8,12
  int lb_r = tid >> 4;               // 0..15  B row within tile
  int lb_c = (tid & 15) * 4;

  for (int k0 = 0; k0 < K; k0 += 16) {
    float4 av = *(const float4*)(A + (size_t)(row0 + la_r) * K + k0 + la_c);
    As[la_c + 0][la_r] = av.x;
    As[la_c + 1][la_r] = av.y;
    As[la_c + 2][la_r] = av.z;
    As[la_c + 3][la_r] = av.w;
    float4 bv = *(const float4*)(W + (size_t)(k0 + lb_r) * N + col0 + lb_c);
    *(float4*)&Bs[lb_r][lb_c] = bv;
    __syncthreads();
#pragma unroll
    for (int kk = 0; kk < 16; kk++) {
      float a0 = As[kk][tr * 4 + 0];
      float a1 = As[kk][tr * 4 + 1];
      float a2 = As[kk][tr * 4 + 2];
      float a3 = As[kk][tr * 4 + 3];
      float4 b = *(const float4*)&Bs[kk][tc * 4];
      acc[0][0] += a0 * b.x; acc[0][1] += a0 * b.y; acc[0][2] += a0 * b.z; acc[0][3] += a0 * b.w;
      acc[1][0] += a1 * b.x; acc[1][1] += a1 * b.y; acc[1][2] += a1 * b.z; acc[1][3] += a1 * b.w;
      acc[2][0] += a2 * b.x; acc[2][1] += a2 * b.y; acc[2][2] += a2 * b.z; acc[2][3] += a2 * b.w;
      acc[3][0] += a3 * b.x; acc[3][1] += a3 * b.y; acc[3][2] += a3 * b.z; acc[3][3] += a3 * b.w;
    }
    __syncthreads();
  }

  float4 bv4 = {0.f, 0.f, 0.f, 0.f};
  if (HAS_BIAS) bv4 = *(const float4*)(bias + col0 + tc * 4);
#pragma unroll
  for (int i = 0; i < 4; i++) {
    int row = row0 + tr * 4 + i;
    float* cp = C + (size_t)row * N + col0 + tc * 4;
    float4 vv;
    vv.x = acc[i][0]; vv.y = acc[i][1]; vv.z = acc[i][2]; vv.w = acc[i][3];
    if (HAS_BIAS) { vv.x += bv4.x; vv.y += bv4.y; vv.z += bv4.z; vv.w += bv4.w; }
    if (DO_GELU) { vv.x = gelu_f(vv.x); vv.y = gelu_f(vv.y); vv.z = gelu_f(vv.z); vv.w = gelu_f(vv.w); }
    if (RESID) {
      float4 old = *(const float4*)cp;
      vv.x += old.x; vv.y += old.y; vv.z += old.z; vv.w += old.w;
    }
    *(float4*)cp = vv;
  }
}

// ---------------------------------------------------------------------------
// rotW2[d][h*32+j] = sum_f Wq[d][h*64+f] * rot[h][f][j]
// f64 fused accumulation, stored f32 (proven: f32 hash == f64 hash buckets).
// ---------------------------------------------------------------------------
__global__ __launch_bounds__(256) void rotw_kernel(const float* __restrict__ Wq,
                                                   const float* __restrict__ rot,
                                                   float* __restrict__ rotW2) {
  int idx = blockIdx.x * 256 + threadIdx.x;   // d*256 + h*32 + j, 512*256 total
  int n = idx & 255;
  int d = idx >> 8;
  int h = n >> 5;
  int j = n & 31;
  double a = 0.0;
#pragma unroll 8
  for (int f = 0; f < 64; f++) {
    a += (double)Wq[(size_t)d * D_ + h * 64 + f] * (double)rot[((size_t)h * 64 + f) * 32 + j];
  }
  rotW2[idx] = (float)a;
}

// ---------------------------------------------------------------------------
// Per-token bucket argmax over [r, -r] (first-index ties, like np.argmax).
// rbuf: [B*S][256] with cols h*32+j.
// ---------------------------------------------------------------------------
__global__ __launch_bounds__(256) void argmax_kernel(const float* __restrict__ rbuf,
                                                     int* __restrict__ buckets) {
  int gid = blockIdx.x * 256 + threadIdx.x;   // b*H*S + h*S + s
  int s = gid & (S_ - 1);
  int bh = gid >> 12;
  int h = bh & (H_ - 1);
  int b = bh >> 3;
  const float* rp = rbuf + ((size_t)b * S_ + s) * 256 + h * 32;
  float r[32];
#pragma unroll
  for (int j4 = 0; j4 < 8; j4++) {
    float4 t4 = *(const float4*)(rp + j4 * 4);
    r[j4 * 4 + 0] = t4.x; r[j4 * 4 + 1] = t4.y;
    r[j4 * 4 + 2] = t4.z; r[j4 * 4 + 3] = t4.w;
  }
  float best = r[0];
  int bi = 0;
#pragma unroll
  for (int j = 1; j < 64; j++) {
    float val = (j < 32) ? r[j] : -r[j - 32];
    if (val > best) { best = val; bi = j; }
  }
  buckets[gid] = bi;
}

// ---------------------------------------------------------------------------
// Stable counting sort by bucket (== argsort(bucket*S + pos)).
// One 64-thread block per (b,h). Each thread owns 64 consecutive positions.
// ---------------------------------------------------------------------------
__global__ __launch_bounds__(64) void sort_kernel(const int* __restrict__ buckets,
                                                  int* __restrict__ st) {
  __shared__ int hist[64][64];   // [thread][bucket]
  __shared__ int boff[64];
  int bh = blockIdx.x;
  const int* bk = buckets + (size_t)bh * S_;
  int* stb = st + (size_t)bh * S_;
  int t = threadIdx.x;
  for (int j = 0; j < 64; j++) hist[t][j] = 0;
  __syncthreads();
  for (int i = 0; i < 64; i++) {
    int s = t * 64 + i;
    hist[t][bk[s]]++;
  }
  __syncthreads();
  // per-bucket exclusive scan across threads (thread j handles bucket j)
  int run = 0;
  for (int tt = 0; tt < 64; tt++) {
    int c = hist[tt][t];
    hist[tt][t] = run;
    run += c;
  }
  boff[t] = run;
  __syncthreads();
  if (t == 0) {
    int acc = 0;
    for (int j = 0; j < 64; j++) { int c = boff[j]; boff[j] = acc; acc += c; }
  }
  __syncthreads();
  for (int i = 0; i < 64; i++) {
    int s = t * 64 + i;
    int bkt = bk[s];
    int pos = boff[bkt] + hist[t][bkt];
    hist[t][bkt] = hist[t][bkt] + 1;
    stb[pos] = s;
  }
}

// ---------------------------------------------------------------------------
// Chunked shared-QK attention. One block per (b,h,chunk).
// Keys/values: chunk n plus chunk n-1 (wrap). 64 queries x 128 keys.
// ---------------------------------------------------------------------------
__global__ __launch_bounds__(256) void attn_kernel(const float* __restrict__ q,
                                                   const float* __restrict__ v,
                                                   const int* __restrict__ st,
                                                   float* __restrict__ o) {
  __shared__ float Ksh[128][64];
  __shared__ float Vsh[128][64];
  int blk = blockIdx.x;
  int n = blk & (NC_ - 1);
  int bh = blk >> 6;
  int h = bh & (H_ - 1);
  int b = bh >> 3;
  const int* stbh = st + (size_t)bh * S_;
  int tid = threadIdx.x;
  int pn = (n + NC_ - 1) & (NC_ - 1);
  for (int i = tid; i < 128 * 16; i += 256) {
    int r = i >> 4, c4 = i & 15;
    int si = (r < 64) ? (n * 64 + r) : (pn * 64 + (r - 64));
    int p = stbh[si];
    size_t base = ((size_t)b * S_ + p) * D_ + h * 64;
    ((float4*)Ksh[r])[c4] = *(const float4*)(q + base + c4 * 4);
    ((float4*)Vsh[r])[c4] = *(const float4*)(v + base + c4 * 4);
  }
  __syncthreads();
  int r = tid >> 2, sub = tid & 3;
  float qr[64];
#pragma unroll
  for (int f4 = 0; f4 < 16; f4++) {
    float4 t4 = ((const float4*)Ksh[r])[f4];
    qr[f4 * 4 + 0] = t4.x; qr[f4 * 4 + 1] = t4.y;
    qr[f4 * 4 + 2] = t4.z; qr[f4 * 4 + 3] = t4.w;
  }
  float lg[32];
  float mx = -1e30f;
#pragma unroll
  for (int kk = 0; kk < 32; kk++) {
    int k = sub * 32 + kk;
    float sdot = 0.f;
#pragma unroll
    for (int f4 = 0; f4 < 16; f4++) {
      float4 kv = ((const float4*)Ksh[k])[f4];
      sdot += qr[f4 * 4 + 0] * kv.x + qr[f4 * 4 + 1] * kv.y
            + qr[f4 * 4 + 2] * kv.z + qr[f4 * 4 + 3] * kv.w;
    }
    sdot *= 0.125f;
    lg[kk] = sdot;
    mx = fmaxf(mx, sdot);
  }
  mx = fmaxf(mx, __shfl_xor(mx, 1));
  mx = fmaxf(mx, __shfl_xor(mx, 2));
  float ssum = 0.f;
#pragma unroll
  for (int kk = 0; kk < 32; kk++) {
    float p = expf(lg[kk] - mx);
    lg[kk] = p;
    ssum += p;
  }
  ssum += __shfl_xor(ssum, 1);
  ssum += __shfl_xor(ssum, 2);
  float acc[64];
#pragma unroll
  for (int f = 0; f < 64; f++) acc[f] = 0.f;
#pragma unroll
  for (int kk = 0; kk < 32; kk++) {
    int k = sub * 32 + kk;
    float w = lg[kk];
#pragma unroll
    for (int f4 = 0; f4 < 16; f4++) {
      float4 vv = ((const float4*)Vsh[k])[f4];
      acc[f4 * 4 + 0] += w * vv.x;
      acc[f4 * 4 + 1] += w * vv.y;
      acc[f4 * 4 + 2] += w * vv.z;
      acc[f4 * 4 + 3] += w * vv.w;
    }
  }
  // reduce-scatter across the 4 sub-lanes (static register indices only)
  float red[32];
#pragma unroll
  for (int j = 0; j < 32; j++) {
    float lo = acc[j], hi = acc[32 + j];
    float keep = (sub & 1) ? hi : lo;
    float send = (sub & 1) ? lo : hi;
    red[j] = keep + __shfl_xor(send, 1);
  }
  float red2[16];
#pragma unroll
  for (int j = 0; j < 16; j++) {
    float lo = red[j], hi = red[16 + j];
    float keep = (sub & 2) ? hi : lo;
    float send = (sub & 2) ? lo : hi;
    red2[j] = keep + __shfl_xor(send, 2);
  }
  int seg = (sub & 1) * 32 + (sub & 2) * 8;   // 0->0, 1->32, 2->16, 3->48
  float inv = 1.0f / ssum;
  int p = stbh[n * 64 + r];
  float* orow = o + ((size_t)b * S_ + p) * D_ + h * 64 + seg;
#pragma unroll
  for (int f4 = 0; f4 < 4; f4++) {
    float4 w4;
    w4.x = red2[f4 * 4 + 0] * inv;
    w4.y = red2[f4 * 4 + 1] * inv;
    w4.z = red2[f4 * 4 + 2] * inv;
    w4.w = red2[f4 * 4 + 3] * inv;
    *(float4*)(orow + f4 * 4) = w4;
  }
}

// ---------------------------------------------------------------------------
extern "C" void kernel_launch(void* const* d_in, const int* in_sizes, int n_in,
                              void* d_out, int out_size, void* d_ws, size_t ws_size,
                              hipStream_t stream) {
  const int*   tokens = (const int*)d_in[0];
  const float* emb    = (const float*)d_in[1];
  const float* rot    = (const float*)d_in[2];
  const float* ln1_s  = (const float*)d_in[3];
  const float* ln1_b  = (const float*)d_in[4];
  const float* Wq     = (const float*)d_in[5];
  const float* Wv     = (const float*)d_in[6];
  const float* Wo     = (const float*)d_in[7];
  const float* ln2_s  = (const float*)d_in[8];
  const float* ln2_b  = (const float*)d_in[9];
  const float* W1     = (const float*)d_in[10];
  const float* b1     = (const float*)d_in[11];
  const float* W2     = (const float*)d_in[12];
  const float* b2     = (const float*)d_in[13];
  const float* lnf_s  = (const float*)d_in[14];
  const float* lnf_b  = (const float*)d_in[15];

  float* x = (float*)d_out;                  // residual stream lives in d_out
  float* ws = (float*)d_ws;
  const size_t RS = (size_t)B_ * S_ * D_;    // 8388608
  float* hbuf = ws;
  float* qbuf = hbuf + RS;
  float* vbuf = qbuf + RS;
  float* obuf = vbuf + RS;
  float* mid  = obuf + RS;                   // 4096*2048 chunk (FFN phase)
  float* rbuf = mid;                         // hash scores [16384][256] (hash phase; aliases mid)
  int* buckets = (int*)(mid + (size_t)4096 * M_);
  int* stbuf   = buckets + B_ * H_ * S_;
  float* rotW2 = (float*)(stbuf + B_ * H_ * S_);   // [512][256] f32 fused hash weight

  const int rows = B_ * S_;                  // 16384

  embed_kernel<<<rows, 128, 0, stream>>>(tokens, emb, x);

  for (int l = 0; l < L_; l++) {
    ln_kernel<<<rows, 64, 0, stream>>>(x, hbuf, ln1_s + (size_t)l * D_, ln1_b + (size_t)l * D_);

    dim3 g1(D_ / 64, rows / 64);
    gemm_kernel<0, 0, 0><<<g1, 256, 0, stream>>>(hbuf, Wq + (size_t)l * D_ * D_, nullptr, qbuf, rows, D_, D_);
    gemm_kernel<0, 0, 0><<<g1, 256, 0, stream>>>(hbuf, Wv + (size_t)l * D_ * D_, nullptr, vbuf, rows, D_, D_);

    rotw_kernel<<<(D_ * 256) / 256, 256, 0, stream>>>(Wq + (size_t)l * D_ * D_,
                                                      rot + (size_t)l * H_ * DH_ * 32, rotW2);
    dim3 gh(256 / 64, rows / 64);
    gemm_kernel<0, 0, 0><<<gh, 256, 0, stream>>>(hbuf, rotW2, nullptr, rbuf, rows, 256, D_);
    argmax_kernel<<<(B_ * H_ * S_) / 256, 256, 0, stream>>>(rbuf, buckets);
    sort_kernel<<<B_ * H_, 64, 0, stream>>>(buckets, stbuf);
    attn_kernel<<<B_ * H_ * NC_, 256, 0, stream>>>(qbuf, vbuf, stbuf, obuf);

    gemm_kernel<0, 1, 0><<<g1, 256, 0, stream>>>(obuf, Wo + (size_t)l * D_ * D_, nullptr, x, rows, D_, D_);

    ln_kernel<<<rows, 64, 0, stream>>>(x, hbuf, ln2_s + (size_t)l * D_, ln2_b + (size_t)l * D_);

    for (int c = 0; c < 4; c++) {
      dim3 gf1(M_ / 64, 4096 / 64);
      gemm_kernel<1, 0, 1><<<gf1, 256, 0, stream>>>(hbuf + (size_t)c * 4096 * D_,
                                                    W1 + (size_t)l * D_ * M_, b1 + (size_t)l * M_,
                                                    mid, 4096, M_, D_);
      dim3 gf2(D_ / 64, 4096 / 64);
      gemm_kernel<1, 1, 0><<<gf2, 256, 0, stream>>>(mid,
                                                    W2 + (size_t)l * M_ * D_, b2 + (size_t)l * D_,
                                                    x + (size_t)c * 4096 * D_, 4096, D_, M_);
    }
  }

  ln_kernel<<<rows, 64, 0, stream>>>(x, x, lnf_s, lnf_b);
}